// Round 1
// baseline (254.728 us; speedup 1.0000x reference)
//
#include <hip/hip_runtime.h>

// One thread per point. Memory-bound elementwise transform.
// Reads: rot(N,4) f32, mod(1) f32, scale(N,2) f32, p_k(N,3) f32, vm(N,16) f32
// Writes: out(N,9) f32
__global__ __launch_bounds__(256) void cov_proj_kernel(
    const float4* __restrict__ rot,     // (N,4) as float4
    const float*  __restrict__ mod,     // (1,)
    const float2* __restrict__ scale,   // (N,2) as float2
    const float*  __restrict__ p_k,     // (N,3)
    const float4* __restrict__ vm,      // (N,16) as 4x float4 per row
    float*        __restrict__ out,     // (N,9)
    int n)
{
    int i = blockIdx.x * blockDim.x + threadIdx.x;
    if (i >= n) return;

    float4 q = rot[i];
    float r = q.x, x = q.y, y = q.z, z = q.w;
    float m = mod[0];
    float2 sc = scale[i];
    float s0 = m * sc.x;
    float s1 = m * sc.y;

    float R00 = 1.0f - 2.0f * (y * y + z * z);
    float R10 = 2.0f * (x * y + r * z);
    float R20 = 2.0f * (x * z - r * y);
    float R01 = 2.0f * (x * y - r * z);
    float R11 = 1.0f - 2.0f * (x * x + z * z);
    float R21 = 2.0f * (y * z + r * x);

    float u0 = s0 * R00, u1 = s0 * R10, u2 = s0 * R20;
    float v0 = s1 * R01, v1 = s1 * R11, v2 = s1 * R21;

    float p0 = p_k[3 * i + 0];
    float p1 = p_k[3 * i + 1];
    float p2 = p_k[3 * i + 2];

    // vm row: vm0 = cols 0..3, vm1 = cols 4..7, vm2 = cols 8..11, vm3 = cols 12..15
    float4 vm0 = vm[4 * i + 0];
    float4 vm1 = vm[4 * i + 1];
    float4 vm2 = vm[4 * i + 2];
    float4 vm3 = vm[4 * i + 3];

    float r1s1 = vm0.x * u0 + vm1.x * u1 + vm2.x * u2;
    float r1s2 = vm0.x * v0 + vm1.x * v1 + vm2.x * v2;
    float r2s1 = vm0.y * u0 + vm1.y * u1 + vm2.y * u2;
    float r2s2 = vm0.y * v0 + vm1.y * v1 + vm2.y * v2;
    float r3s1 = vm0.z * u0 + vm1.z * u1 + vm2.z * u2;
    float r3s2 = vm0.z * v0 + vm1.z * v1 + vm2.z * v2;

    float r1p = vm0.x * p0 + vm1.x * p1 + vm2.x * p2 + vm3.x;
    float r2p = vm0.y * p0 + vm1.y * p1 + vm2.y * p2 + vm3.y;
    float r3p = vm0.z * p0 + vm1.z * p1 + vm2.z * p2 + vm3.z;

    float* o = out + (size_t)9 * i;
    o[0] = r1s1;
    o[1] = r1s2;
    o[2] = r1p;
    o[3] = r2s1;
    o[4] = r2s2;
    o[5] = r2p;
    o[6] = r3s1;
    o[7] = r3s2;
    o[8] = r3p;
}

extern "C" void kernel_launch(void* const* d_in, const int* in_sizes, int n_in,
                              void* d_out, int out_size, void* d_ws, size_t ws_size,
                              hipStream_t stream) {
    const float4* rot   = (const float4*)d_in[0];
    const float*  mod   = (const float*)d_in[1];
    const float2* scale = (const float2*)d_in[2];
    const float*  p_k   = (const float*)d_in[3];
    const float4* vm    = (const float4*)d_in[4];
    float* out = (float*)d_out;

    int n = in_sizes[0] / 4;  // rot has N*4 elements
    int block = 256;
    int grid = (n + block - 1) / block;
    cov_proj_kernel<<<grid, block, 0, stream>>>(rot, mod, scale, p_k, vm, out, n);
}

// Round 2
// 253.940 us; speedup vs baseline: 1.0031x; 1.0031x over previous
//
#include <hip/hip_runtime.h>

// One thread per point; LDS-staged coalesced output stores.
// Reads: rot(N,4) f32, mod(1) f32, scale(N,2) f32, p_k(N,3) f32, vm(N,16) f32
// Writes: out(N,9) f32 via LDS transpose -> contiguous float4 stores.
__global__ __launch_bounds__(256) void cov_proj_kernel(
    const float4* __restrict__ rot,     // (N,4) as float4
    const float*  __restrict__ mod,     // (1,)
    const float2* __restrict__ scale,   // (N,2) as float2
    const float*  __restrict__ p_k,     // (N,3)
    const float4* __restrict__ vm,      // (N,16) as 4x float4 per row
    float*        __restrict__ out,     // (N,9)
    int n)
{
    __shared__ float lds_out[256 * 9];  // 9 KiB

    const int t = threadIdx.x;
    const int base = blockIdx.x * 256;
    const int i = base + t;

    if (i < n) {
        float4 q = rot[i];
        float r = q.x, x = q.y, y = q.z, z = q.w;
        float m = mod[0];
        float2 sc = scale[i];
        float s0 = m * sc.x;
        float s1 = m * sc.y;

        float R00 = 1.0f - 2.0f * (y * y + z * z);
        float R10 = 2.0f * (x * y + r * z);
        float R20 = 2.0f * (x * z - r * y);
        float R01 = 2.0f * (x * y - r * z);
        float R11 = 1.0f - 2.0f * (x * x + z * z);
        float R21 = 2.0f * (y * z + r * x);

        float u0 = s0 * R00, u1 = s0 * R10, u2 = s0 * R20;
        float v0 = s1 * R01, v1 = s1 * R11, v2 = s1 * R21;

        float p0 = p_k[3 * i + 0];
        float p1 = p_k[3 * i + 1];
        float p2 = p_k[3 * i + 2];

        float4 vm0 = vm[4 * i + 0];
        float4 vm1 = vm[4 * i + 1];
        float4 vm2 = vm[4 * i + 2];
        float4 vm3 = vm[4 * i + 3];

        float* o = &lds_out[9 * t];     // banks (9t+j)%32: <=2 lanes/bank -> free
        o[0] = vm0.x * u0 + vm1.x * u1 + vm2.x * u2;
        o[1] = vm0.x * v0 + vm1.x * v1 + vm2.x * v2;
        o[2] = vm0.x * p0 + vm1.x * p1 + vm2.x * p2 + vm3.x;
        o[3] = vm0.y * u0 + vm1.y * u1 + vm2.y * u2;
        o[4] = vm0.y * v0 + vm1.y * v1 + vm2.y * v2;
        o[5] = vm0.y * p0 + vm1.y * p1 + vm2.y * p2 + vm3.y;
        o[6] = vm0.z * u0 + vm1.z * u1 + vm2.z * u2;
        o[7] = vm0.z * v0 + vm1.z * v1 + vm2.z * v2;
        o[8] = vm0.z * p0 + vm1.z * p1 + vm2.z * p2 + vm3.z;
    }
    __syncthreads();

    const int points = min(256, n - base);
    const size_t out_base = (size_t)base * 9;

    if (points == 256) {
        // Full block: 2304 floats = 576 float4, contiguous & 16B-aligned
        // (out_base*4 = blockIdx*9216 bytes, 9216 % 16 == 0).
        const float4* lo4 = (const float4*)lds_out;
        float4* go4 = (float4*)(out + out_base);
        #pragma unroll
        for (int k = t; k < 576; k += 256) go4[k] = lo4[k];
    } else {
        const int total = points * 9;
        for (int k = t; k < total; k += 256) out[out_base + k] = lds_out[k];
    }
}

extern "C" void kernel_launch(void* const* d_in, const int* in_sizes, int n_in,
                              void* d_out, int out_size, void* d_ws, size_t ws_size,
                              hipStream_t stream) {
    const float4* rot   = (const float4*)d_in[0];
    const float*  mod   = (const float*)d_in[1];
    const float2* scale = (const float2*)d_in[2];
    const float*  p_k   = (const float*)d_in[3];
    const float4* vm    = (const float4*)d_in[4];
    float* out = (float*)d_out;

    int n = in_sizes[0] / 4;  // rot has N*4 elements
    int block = 256;
    int grid = (n + block - 1) / block;
    cov_proj_kernel<<<grid, block, 0, stream>>>(rot, mod, scale, p_k, vm, out, n);
}